// Round 16
// baseline (877.450 us; speedup 1.0000x reference)
//
#include <hip/hip_runtime.h>

// ---------------------------------------------------------------------------
// WordEncoder round 16: round-15 + gemm_res_ln retiled BM=32 (grid 1024,
// 4 blocks/CU vs 2 — continuing the round-9 occupancy-scaling win).
// ---------------------------------------------------------------------------

#define S_LEN 8192
#define BATCH 4
#define DMODEL 256
#define NHEAD 8
#define WIN 64
#define NWIN 128
#define NLAYER 6
#define FFDIM 1024
#define MROWS (BATCH * S_LEN)

typedef float __attribute__((ext_vector_type(4))) f32x4;
typedef unsigned int __attribute__((ext_vector_type(2))) u32x2;
typedef unsigned short u16;
typedef unsigned short __attribute__((ext_vector_type(4))) u16x4;
typedef unsigned short __attribute__((ext_vector_type(8))) u16x8;

__device__ __forceinline__ u16 f2bf(float f) {
  unsigned u = __builtin_bit_cast(unsigned, f);
  u += 0x7fffu + ((u >> 16) & 1u);
  return (u16)(u >> 16);
}

__device__ __forceinline__ unsigned cvt_pk_bf16(float lo, float hi) {
  unsigned r;
  asm("v_cvt_pk_bf16_f32 %0, %1, %2" : "=v"(r) : "v"(lo), "v"(hi));
  return r;
}
__device__ __forceinline__ u32x2 pack_bf16x4(f32x4 v) {
  u32x2 o;
  o[0] = cvt_pk_bf16(v[0], v[1]);
  o[1] = cvt_pk_bf16(v[2], v[3]);
  return o;
}
__device__ __forceinline__ f32x4 unpack_bf16x4(u16x4 h) {
  f32x4 o;
  o[0] = __builtin_bit_cast(float, (unsigned)h[0] << 16);
  o[1] = __builtin_bit_cast(float, (unsigned)h[1] << 16);
  o[2] = __builtin_bit_cast(float, (unsigned)h[2] << 16);
  o[3] = __builtin_bit_cast(float, (unsigned)h[3] << 16);
  return o;
}

__device__ __forceinline__ float exp2_f(float x) {
  float r;
  asm("v_exp_f32 %0, %1" : "=v"(r) : "v"(x));
  return r;
}

// mfma16(d, P, Q): lane holds D[row = Q's l15-space][cols = P's l15-space
// at l4*4+j]  (validated rounds 3-15)
__device__ __forceinline__ void mfma16(f32x4& d, f32x4 a, f32x4 b) {
  asm volatile("v_mfma_f32_16x16x32_bf16 %0, %1, %2, %0"
               : "+v"(d) : "v"(a), "v"(b));
}
#define MFMA_FENCE() asm volatile("s_nop 7\n\ts_nop 7")

__device__ __forceinline__ void gload_lds16(const void* g, void* l) {
  __builtin_amdgcn_global_load_lds(
      (__attribute__((address_space(1))) void*)g,
      (__attribute__((address_space(3))) void*)l, 16, 0, 0);
}

__device__ __forceinline__ float gelu_f(float t) {
  float u = 0.7978845608028654f * (t + 0.044715f * t * t * t);
  float e = __expf(-2.0f * u);
  return t * __builtin_amdgcn_rcpf(1.0f + e);
}

// -------------------------------------------------- embed + LN1(layer 0) ---
__global__ __launch_bounds__(256) void embed_ln_kernel(
    const int* __restrict__ ids, const float* __restrict__ emb,
    const float* __restrict__ pos, const float* __restrict__ g,
    const float* __restrict__ b, u16* __restrict__ x, u16* __restrict__ xb) {
  int wid = threadIdx.x >> 6, lane = threadIdx.x & 63;
  int r = blockIdx.x * 4 + wid;
  int s = r & (S_LEN - 1);
  int id = ids[r];
  f32x4 e = *(const f32x4*)(emb + (size_t)id * DMODEL + lane * 4);
  f32x4 p = *(const f32x4*)(pos + (size_t)s * DMODEL + lane * 4);
  f32x4 v = e + p;
  *(u32x2*)(x + (size_t)r * DMODEL + lane * 4) = pack_bf16x4(v);
  float sm = v[0] + v[1] + v[2] + v[3];
  float q = v[0] * v[0] + v[1] * v[1] + v[2] * v[2] + v[3] * v[3];
  for (int off = 32; off; off >>= 1) {
    sm += __shfl_xor(sm, off, 64);
    q += __shfl_xor(q, off, 64);
  }
  float mean = sm * (1.0f / DMODEL);
  float var = q * (1.0f / DMODEL) - mean * mean;
  float rs = rsqrtf(var + 1e-5f);
  f32x4 gg = *(const f32x4*)(g + lane * 4);
  f32x4 bb = *(const f32x4*)(b + lane * 4);
  f32x4 o;
  for (int j = 0; j < 4; ++j) o[j] = (v[j] - mean) * rs * gg[j] + bb[j];
  *(u32x2*)(xb + (size_t)r * DMODEL + lane * 4) = pack_bf16x4(o);
}

// ----------------------------------------------------------------- zero ----
__global__ void zero_kernel(float* __restrict__ p, int n4) {
  int i = blockIdx.x * blockDim.x + threadIdx.x;
  int stride = gridDim.x * blockDim.x;
  f32x4 z = {0.f, 0.f, 0.f, 0.f};
  for (; i < n4; i += stride) ((f32x4*)p)[i] = z;
}

// ------------------------------ tiled weight transpose+cast (via LDS) ------
__global__ __launch_bounds__(256) void tcast_tile_kernel(
    const float* __restrict__ wq, const float* __restrict__ wk,
    const float* __restrict__ wv, const float* __restrict__ wo,
    const float* __restrict__ w1, const float* __restrict__ w2,
    u16* __restrict__ WqkvT, u16* __restrict__ WoT,
    u16* __restrict__ W1T, u16* __restrict__ W2T) {
  __shared__ u16 Ts[64 * 72];

  int tile = blockIdx.x;
  const float* srcBase;
  u16* dstBase;
  int K, N, rowOff, tileK, tileN;

  if (tile < 384) {
    int fam = tile / 96, local = tile % 96;
    int l = local >> 4, t = local & 15;
    K = 256;
    N = 256;
    tileK = t >> 2;
    tileN = t & 3;
    if (fam < 3) {
      const float* s = (fam == 0) ? wq : (fam == 1) ? wk : wv;
      srcBase = s + (size_t)l * 65536;
      dstBase = WqkvT + (size_t)l * 768 * 256;
      rowOff = fam * 256;
    } else {
      srcBase = wo + (size_t)l * 65536;
      dstBase = WoT + (size_t)l * 65536;
      rowOff = 0;
    }
  } else if (tile < 768) {
    int local = tile - 384;
    int l = local >> 6, t = local & 63;
    K = 256;
    N = 1024;
    tileK = t >> 4;
    tileN = t & 15;
    srcBase = w1 + (size_t)l * 262144;
    dstBase = W1T + (size_t)l * 262144;
    rowOff = 0;
  } else {
    int local = tile - 768;
    int l = local >> 6, t = local & 63;
    K = 1024;
    N = 256;
    tileK = t >> 2;
    tileN = t & 3;
    srcBase = w2 + (size_t)l * 262144;
    dstBase = W2T + (size_t)l * 262144;
    rowOff = 0;
  }

  int k0 = tileK * 64, n0 = tileN * 64;
  int tid = threadIdx.x;

#pragma unroll
  for (int p = 0; p < 4; ++p) {
    int ch = tid + p * 256;
    int r = ch >> 4, c4 = (ch & 15) * 4;
    f32x4 v = *(const f32x4*)(srcBase + (size_t)(k0 + r) * N + n0 + c4);
#pragma unroll
    for (int j = 0; j < 4; ++j) Ts[(c4 + j) * 72 + r] = f2bf(v[j]);
  }
  __syncthreads();

#pragma unroll
  for (int p = 0; p < 2; ++p) {
    int ch = tid + p * 256;
    int n = ch >> 3, kc = ch & 7;
    *(u16x8*)(dstBase + (size_t)(rowOff + n0 + n) * K + k0 + kc * 8) =
        *(const u16x8*)(Ts + n * 72 + kc * 8);
  }
}

// ------------------------------------------------------ plain GEMM (bf16) --
// 128x128 tile, 4 waves (2x2), BK=64, swizzled staged LDS (round-11 verbatim).
template <bool GELU_ACT, bool HAS_BIAS, bool QKV>
__global__ __launch_bounds__(256) void gemm_bf16(
    const u16* __restrict__ A, const u16* __restrict__ Bt,
    u16* __restrict__ C, u16* __restrict__ Vt, const float* __restrict__ bias,
    int N, int K, int nx) {
  __shared__ u16 As[128 * 64];
  __shared__ u16 Bs[128 * 64];

  int nwg = gridDim.x;
  int bid = blockIdx.x;
  int w8 = (bid & 7) * (nwg >> 3) + (bid >> 3);
  int cx = w8 % nx, ry = w8 / nx;
  int bm = ry * 128, bn = cx * 128;

  int tid = threadIdx.x, lane = tid & 63, wid = tid >> 6;
  int l15 = lane & 15, l4 = lane >> 4;
  int wm = wid >> 1, wn = wid & 1;

  const u16* Ab = A + (size_t)bm * K;
  const u16* Bb = Bt + (size_t)bn * K;

  f32x4 acc[4][4] = {};

  for (int kt = 0; kt < K; kt += 64) {
#pragma unroll
    for (int i = 0; i < 4; ++i) {
      int s = tid + i * 256;
      int r = s >> 3, c = (s & 7) ^ (r & 7);
      gload_lds16(Ab + (size_t)r * K + kt + c * 8,
                  (char*)As + (wid * 64 + i * 256) * 16);
    }
#pragma unroll
    for (int i = 0; i < 4; ++i) {
      int s = tid + i * 256;
      int r = s >> 3, c = (s & 7) ^ (r & 7);
      gload_lds16(Bb + (size_t)r * K + kt + c * 8,
                  (char*)Bs + (wid * 64 + i * 256) * 16);
    }
    __syncthreads();
#pragma unroll
    for (int t = 0; t < 2; ++t) {
      f32x4 af[4], bf[4];
#pragma unroll
      for (int m = 0; m < 4; ++m) {
        int r = wm * 64 + m * 16 + l15;
        af[m] = ((const f32x4*)As)[r * 8 + ((t * 4 + l4) ^ (r & 7))];
      }
#pragma unroll
      for (int n = 0; n < 4; ++n) {
        int r = wn * 64 + n * 16 + l15;
        bf[n] = ((const f32x4*)Bs)[r * 8 + ((t * 4 + l4) ^ (r & 7))];
      }
#pragma unroll
      for (int m = 0; m < 4; ++m)
#pragma unroll
        for (int n = 0; n < 4; ++n) mfma16(acc[m][n], bf[n], af[m]);
    }
    __syncthreads();
  }
  MFMA_FENCE();

  int colB = bn + wn * 64;
  if (QKV && colB >= 512) {
#pragma unroll
    for (int m = 0; m < 4; ++m) {
      int row = bm + wm * 64 + m * 16 + l15;
      int bb = row >> 13, s = row & (S_LEN - 1);
#pragma unroll
      for (int n = 0; n < 4; ++n)
#pragma unroll
        for (int j = 0; j < 4; ++j) {
          int col = colB + n * 16 + l4 * 4 + j;
          Vt[((size_t)(bb * 256 + (col - 512))) * S_LEN + s] =
              f2bf(acc[m][n][j]);
        }
    }
    return;
  }
  f32x4 bv[4];
#pragma unroll
  for (int n = 0; n < 4; ++n)
    bv[n] = HAS_BIAS ? *(const f32x4*)(bias + colB + n * 16 + l4 * 4)
                     : (f32x4){0.f, 0.f, 0.f, 0.f};
#pragma unroll
  for (int m = 0; m < 4; ++m) {
    int row = bm + wm * 64 + m * 16 + l15;
#pragma unroll
    for (int n = 0; n < 4; ++n) {
      f32x4 v = acc[m][n] + bv[n];
      if (GELU_ACT) {
#pragma unroll
        for (int j = 0; j < 4; ++j) v[j] = gelu_f(v[j]);
      }
      *(u32x2*)(C + (size_t)row * N + colB + n * 16 + l4 * 4) = pack_bf16x4(v);
    }
  }
}

// ------------------------------------- GEMM + residual (+bias) + LN fused --
// BM=32, BN=256 (full row), 4 waves (col-split), BK=64. Grid 1024 ->
// 4 blocks/CU (34 KB LDS). x is bf16.
template <bool DO_LN>
__global__ __launch_bounds__(256) void gemm_res_ln(
    const u16* __restrict__ A, const u16* __restrict__ Bt,
    u16* __restrict__ x, u16* __restrict__ xb,
    const float* __restrict__ bias, const float* __restrict__ g,
    const float* __restrict__ b, int K) {
  __shared__ u16 As[32 * 64];    // 4 KB
  __shared__ u16 Bs[256 * 64];   // 32 KB
  __shared__ float redS[32][4];
  __shared__ float redQ[32][4];

  int nwg = gridDim.x;  // 1024
  int bid = blockIdx.x;
  int bm = ((bid & 7) * (nwg >> 3) + (bid >> 3)) * 32;

  int tid = threadIdx.x, lane = tid & 63, wid = tid >> 6;
  int l15 = lane & 15, l4 = lane >> 4;

  const u16* Ab = A + (size_t)bm * K;
  f32x4 acc[2][4] = {};

  for (int kt = 0; kt < K; kt += 64) {
    {  // A: 32x64 = 256 chunks, one per thread
      int r = tid >> 3, c = (tid & 7) ^ (r & 7);
      gload_lds16(Ab + (size_t)r * K + kt + c * 8, (char*)As + tid * 16);
    }
#pragma unroll
    for (int i = 0; i < 8; ++i) {  // B: 2048 chunks
      int s = tid + i * 256;
      int r = s >> 3, c = (s & 7) ^ (r & 7);
      gload_lds16(Bt + (size_t)r * K + kt + c * 8,
                  (char*)Bs + (wid * 64 + i * 256) * 16);
    }
    __syncthreads();
#pragma unroll
    for (int t = 0; t < 2; ++t) {
      f32x4 af[2], bf[4];
#pragma unroll
      for (int m = 0; m < 2; ++m) {
        int r = m * 16 + l15;
        af[m] = ((const f32x4*)As)[r * 8 + ((t * 4 + l4) ^ (r & 7))];
      }
#pragma unroll
      for (int n = 0; n < 4; ++n) {
        int r = wid * 64 + n * 16 + l15;
        bf[n] = ((const f32x4*)Bs)[r * 8 + ((t * 4 + l4) ^ (r & 7))];
      }
#pragma unroll
      for (int m = 0; m < 2; ++m)
#pragma unroll
        for (int n = 0; n < 4; ++n) mfma16(acc[m][n], bf[n], af[m]);
    }
    __syncthreads();
  }
  MFMA_FENCE();

  int colB = wid * 64;
  f32x4 bv[4];
#pragma unroll
  for (int n = 0; n < 4; ++n)
    bv[n] = bias ? *(const f32x4*)(bias + colB + n * 16 + l4 * 4)
                 : (f32x4){0.f, 0.f, 0.f, 0.f};

#pragma unroll
  for (int m = 0; m < 2; ++m) {
    int r = m * 16 + l15;
    size_t rowoff = (size_t)(bm + r) * DMODEL + colB;
    float s = 0.f, q = 0.f;
#pragma unroll
    for (int n = 0; n < 4; ++n) {
      f32x4 xv = unpack_bf16x4(*(const u16x4*)(x + rowoff + n * 16 + l4 * 4));
      f32x4 v = acc[m][n] + bv[n] + xv;
      acc[m][n] = v;
      s += v[0] + v[1] + v[2] + v[3];
      q += v[0] * v[0] + v[1] * v[1] + v[2] * v[2] + v[3] * v[3];
    }
    if (DO_LN) {
      s += __shfl_xor(s, 16, 64);
      s += __shfl_xor(s, 32, 64);
      q += __shfl_xor(q, 16, 64);
      q += __shfl_xor(q, 32, 64);
      if (l4 == 0) {
        redS[r][wid] = s;
        redQ[r][wid] = q;
      }
    }
  }
  if (DO_LN) __syncthreads();

  f32x4 gv[4], bbv[4];
  if (DO_LN) {
#pragma unroll
    for (int n = 0; n < 4; ++n) {
      gv[n] = *(const f32x4*)(g + colB + n * 16 + l4 * 4);
      bbv[n] = *(const f32x4*)(b + colB + n * 16 + l4 * 4);
    }
  }
#pragma unroll
  for (int m = 0; m < 2; ++m) {
    int r = m * 16 + l15;
    size_t rowoff = (size_t)(bm + r) * DMODEL + colB;
    float mean = 0.f, rs = 0.f;
    if (DO_LN) {
      f32x4 sv = *(const f32x4*)redS[r];
      f32x4 qv = *(const f32x4*)redQ[r];
      float ssum = sv[0] + sv[1] + sv[2] + sv[3];
      float qsum = qv[0] + qv[1] + qv[2] + qv[3];
      mean = ssum * (1.0f / DMODEL);
      float var = qsum * (1.0f / DMODEL) - mean * mean;
      rs = rsqrtf(var + 1e-5f);
    }
#pragma unroll
    for (int n = 0; n < 4; ++n) {
      f32x4 v = acc[m][n];
      *(u32x2*)(x + rowoff + n * 16 + l4 * 4) = pack_bf16x4(v);
      if (DO_LN) {
        f32x4 o;
#pragma unroll
        for (int j = 0; j < 4; ++j)
          o[j] = (v[j] - mean) * rs * gv[n][j] + bbv[n][j];
        *(u32x2*)(xb + rowoff + n * 16 + l4 * 4) = pack_bf16x4(o);
      }
    }
  }
}

// ------------------------------------------------------------ attention ----
__global__ __launch_bounds__(256, 4) void attn_kernel(
    const u16* __restrict__ qkv, const u16* __restrict__ vt,
    const int* __restrict__ amask, u16* __restrict__ ao) {
  int win = blockIdx.x, h = blockIdx.y, b = blockIdx.z;
  int tid = threadIdx.x, lane = tid & 63, wid = tid >> 6;
  int l15 = lane & 15, l4 = lane >> 4;

  __shared__ u16 KPs[192 * 64];  // Ks [96][64] / Ps [192][64]
  __shared__ u16 Vts[96 * 64];
  __shared__ float bias[192];

  int t0 = win * WIN - WIN;

  if (tid < 192) {
    int t = t0 + tid;
    bias[tid] =
        (t >= 0 && t < S_LEN && amask[b * S_LEN + t] != 0) ? 0.0f : -1e9f;
  }
#pragma unroll
  for (int it = 0; it < 3; ++it) {
    int c = it * 256 + tid;
    int k = c >> 2, j = c & 3;
    int t = t0 + k;
    t = t < 0 ? 0 : (t >= S_LEN ? S_LEN - 1 : t);
    f32x4 kd = *(const f32x4*)(qkv + (size_t)(b * S_LEN + t) * 768 + 256 +
                               h * 32 + j * 8);
    int row = k >> 1;
    int cc = (((k & 1) << 2) | j) ^ (row & 7);
    *(f32x4*)(KPs + row * 64 + cc * 8) = kd;
  }
#pragma unroll
  for (int it = 0; it < 3; ++it) {
    int c = it * 256 + tid;
    int d = c / 24, kc = c - d * 24;
    int ts = t0 + kc * 8;
    ts = ts < 0 ? 0 : (ts > S_LEN - 8 ? S_LEN - 8 : ts);
    f32x4 vd = *(const f32x4*)(vt + ((size_t)((b * 8 + h) * 32 + d)) * S_LEN + ts);
    int row = d * 3 + (kc >> 3);
    int cc = (kc & 7) ^ (row & 7);
    *(f32x4*)(Vts + row * 64 + cc * 8) = vd;
  }
  __syncthreads();

  int qrow = b * S_LEN + win * WIN + wid * 16 + l15;
  f32x4 aq = *(const f32x4*)(qkv + (size_t)qrow * 768 + h * 32 + l4 * 8);

  f32x4 sacc[12] = {};
  int krb = l15 >> 1;
  int kcc = (((l15 & 1) << 2) | l4) ^ (krb & 7);
#pragma unroll
  for (int f = 0; f < 12; ++f) {
    f32x4 bk = *(const f32x4*)(KPs + (f * 8 + krb) * 64 + kcc * 8);
    mfma16(sacc[f], bk, aq);
  }
  MFMA_FENCE();

  const float scale2 = 0.17677669529663687f * 1.4426950408889634f;
  float mrow = -1e30f;
#pragma unroll
  for (int f = 0; f < 12; ++f) {
    f32x4 bi = *(const f32x4*)&bias[f * 16 + l4 * 4];
#pragma unroll
    for (int j = 0; j < 4; ++j) {
      float sv = fmaf(sacc[f][j], scale2, bi[j]);
      sacc[f][j] = sv;
      mrow = fmaxf(mrow, sv);
    }
  }
  mrow = fmaxf(mrow, __shfl_xor(mrow, 16, 64));
  mrow = fmaxf(mrow, __shfl_xor(mrow, 32, 64));

  float ssum = 0.f;
#pragma unroll
  for (int f = 0; f < 12; ++f)
#pragma unroll
    for (int j = 0; j < 4; ++j) {
      float p = exp2_f(sacc[f][j] - mrow);
      sacc[f][j] = p;
      ssum += p;
    }
  ssum += __shfl_xor(ssum, 16, 64);
  ssum += __shfl_xor(ssum, 32, 64);

  __syncthreads();

  int q = wid * 16 + l15;
#pragma unroll
  for (int f = 0; f < 12; ++f) {
    u32x2 pk;
    pk[0] = cvt_pk_bf16(sacc[f][0], sacc[f][1]);
    pk[1] = cvt_pk_bf16(sacc[f][2], sacc[f][3]);
    int kc = f * 2 + (l4 >> 1);
    int row = q * 3 + (kc >> 3);
    int cc = (kc & 7) ^ (row & 7);
    *(u32x2*)(KPs + row * 64 + cc * 8 + (l4 & 1) * 4) = pk;
  }
  __syncthreads();

  f32x4 oacc[2] = {};
#pragma unroll
  for (int kk = 0; kk < 6; ++kk) {
    int kc = kk * 4 + l4;
    int rowp = q * 3 + (kc >> 3);
    int ccp = (kc & 7) ^ (rowp & 7);
    f32x4 ap = *(const f32x4*)(KPs + rowp * 64 + ccp * 8);
#pragma unroll
    for (int nf = 0; nf < 2; ++nf) {
      int d = nf * 16 + l15;
      int rowv = d * 3 + (kc >> 3);
      int ccv = (kc & 7) ^ (rowv & 7);
      f32x4 bvv = *(const f32x4*)(Vts + rowv * 64 + ccv * 8);
      mfma16(oacc[nf], bvv, ap);
    }
  }
  MFMA_FENCE();

  float invv = 1.0f / ssum;
  size_t obase = (size_t)qrow * 256 + h * 32;
#pragma unroll
  for (int nf = 0; nf < 2; ++nf) {
    f32x4 v = oacc[nf] * invv;
    *(u32x2*)(ao + obase + nf * 16 + l4 * 4) = pack_bf16x4(v);
  }
}

// ------------------------------------------------------------- scan --------
__global__ __launch_bounds__(256) void scan_kernel(const int* __restrict__ wsrt,
                                                   int* __restrict__ tgt) {
  __shared__ int part[256];
  int b = blockIdx.x, tid = threadIdx.x;
  const int* src = wsrt + b * S_LEN;
  int* dst = tgt + b * S_LEN;
  int base = tid * 32;
  int loc[32];
  int s = 0;
#pragma unroll
  for (int i = 0; i < 32; ++i) {
    loc[i] = src[base + i];
    s += loc[i];
  }
  part[tid] = s;
  __syncthreads();
  for (int off = 1; off < 256; off <<= 1) {
    int v = (tid >= off) ? part[tid - off] : 0;
    __syncthreads();
    part[tid] += v;
    __syncthreads();
  }
  int cum = part[tid] - s;
#pragma unroll
  for (int i = 0; i < 32; ++i) {
    cum += loc[i];
    dst[base + i] = (loc[i] > 0) ? (cum - 1) : -1;
  }
}

// ------------------------------------------------- final LN + gather -------
__global__ __launch_bounds__(64) void gather_ln_kernel(
    const u16* __restrict__ x, const int* __restrict__ tgt,
    const float* __restrict__ g, const float* __restrict__ b,
    float* __restrict__ out) {
  int r = blockIdx.x;
  int tg = tgt[r];
  if (tg < 0) return;
  int bIdx = r >> 13;
  int lane = threadIdx.x;
  f32x4 v = unpack_bf16x4(*(const u16x4*)(x + (size_t)r * DMODEL + lane * 4));
  float s = v[0] + v[1] + v[2] + v[3];
  float q = v[0] * v[0] + v[1] * v[1] + v[2] * v[2] + v[3] * v[3];
  for (int off = 32; off; off >>= 1) {
    s += __shfl_xor(s, off, 64);
    q += __shfl_xor(q, off, 64);
  }
  float mean = s * (1.0f / DMODEL);
  float var = q * (1.0f / DMODEL) - mean * mean;
  float rs = rsqrtf(var + 1e-5f);
  f32x4 gg = *(const f32x4*)(g + lane * 4);
  f32x4 bb = *(const f32x4*)(b + lane * 4);
  f32x4 o;
  for (int j = 0; j < 4; ++j) o[j] = (v[j] - mean) * rs * gg[j] + bb[j];
  *(f32x4*)(out + (size_t)(bIdx * S_LEN + tg) * DMODEL + lane * 4) = o;
}

// ---------------------------------------------------------------------------
extern "C" void kernel_launch(void* const* d_in, const int* in_sizes, int n_in,
                              void* d_out, int out_size, void* d_ws,
                              size_t ws_size, hipStream_t stream) {
  const int* ids = (const int*)d_in[0];
  const int* amask = (const int*)d_in[1];
  const int* wstart = (const int*)d_in[2];
  const float* emb = (const float*)d_in[3];
  const float* pos = (const float*)d_in[4];
  const float* ln1g = (const float*)d_in[5];
  const float* ln1b = (const float*)d_in[6];
  const float* wq = (const float*)d_in[7];
  const float* wk = (const float*)d_in[8];
  const float* wv = (const float*)d_in[9];
  const float* wo = (const float*)d_in[10];
  const float* ln2g = (const float*)d_in[11];
  const float* ln2b = (const float*)d_in[12];
  const float* w1 = (const float*)d_in[13];
  const float* b1 = (const float*)d_in[14];
  const float* w2 = (const float*)d_in[15];
  const float* b2 = (const float*)d_in[16];
  const float* lnfg = (const float*)d_in[17];
  const float* lnfb = (const float*)d_in[18];

  char* ws = (char*)d_ws;
  const size_t OFF_X = 0;              // bf16 [32768][256]
  const size_t OFF_XB = 33554432;      // bf16 [32768][256]
  const size_t OFF_AO = 50331648;      // bf16 [32768][256]
  const size_t OFF_BIG = 67108864;     // bf16 qkv [32768][768]
  const size_t OFF_VT = 117440512;     // bf16 [256][8192] V^T
  const size_t OFF_WQKVT = 134217728;  // bf16 [6][768][256]
  const size_t OFF_WOT = 136577024;    // bf16 [6][256][256]
  const size_t OFF_W1T = 137363456;    // bf16 [6][1024][256]
  const size_t OFF_W2T = 140509184;    // bf16 [6][256][1024]
  const size_t OFF_TGT = 143654912;    // int [32768]
  const size_t NEEDED = 143785984;
  if (ws_size < NEEDED) return;

  u16* x = (u16*)(ws + OFF_X);
  u16* xb = (u16*)(ws + OFF_XB);
  u16* ao = (u16*)(ws + OFF_AO);
  u16* big = (u16*)(ws + OFF_BIG);
  u16* vt = (u16*)(ws + OFF_VT);
  u16* WqkvT = (u16*)(ws + OFF_WQKVT);
  u16* WoT = (u16*)(ws + OFF_WOT);
  u16* W1T = (u16*)(ws + OFF_W1T);
  u16* W2T = (u16*)(ws + OFF_W2T);
  int* tgt = (int*)(ws + OFF_TGT);

  tcast_tile_kernel<<<1152, 256, 0, stream>>>(wq, wk, wv, wo, w1, w2,
                                              WqkvT, WoT, W1T, W2T);

  embed_ln_kernel<<<MROWS / 4, 256, 0, stream>>>(ids, emb, pos, ln1g, ln1b, x, xb);
  zero_kernel<<<2048, 256, 0, stream>>>((float*)d_out, out_size / 4);
  scan_kernel<<<BATCH, 256, 0, stream>>>(wstart, tgt);

  for (int l = 0; l < NLAYER; ++l) {
    gemm_bf16<false, false, true><<<1536, 256, 0, stream>>>(
        xb, WqkvT + (size_t)l * 768 * 256, big, vt, nullptr, 768, 256, 6);
    attn_kernel<<<dim3(NWIN, NHEAD, BATCH), 256, 0, stream>>>(big, vt, amask, ao);
    gemm_res_ln<true><<<MROWS / 32, 256, 0, stream>>>(
        ao, WoT + (size_t)l * 256 * 256, x, xb, nullptr,
        ln2g + l * DMODEL, ln2b + l * DMODEL, 256);
    gemm_bf16<true, true, false><<<2048, 256, 0, stream>>>(
        xb, W1T + (size_t)l * 1024 * 256, big, nullptr, b1 + l * FFDIM, 1024, 256, 8);
    if (l < NLAYER - 1) {
      gemm_res_ln<true><<<MROWS / 32, 256, 0, stream>>>(
          big, W2T + (size_t)l * 256 * 1024, x, xb, b2 + l * DMODEL,
          ln1g + (l + 1) * DMODEL, ln1b + (l + 1) * DMODEL, 1024);
    } else {
      gemm_res_ln<false><<<MROWS / 32, 256, 0, stream>>>(
          big, W2T + (size_t)l * 256 * 1024, x, nullptr, b2 + l * DMODEL,
          nullptr, nullptr, 1024);
    }
  }

  gather_ln_kernel<<<MROWS, 64, 0, stream>>>(x, tgt, lnfg, lnfb, (float*)d_out);
}

// Round 17
// 818.086 us; speedup vs baseline: 1.0726x; 1.0726x over previous
//
#include <hip/hip_runtime.h>

// ---------------------------------------------------------------------------
// WordEncoder round 17: exact revert to round-15 (820 µs best-known).
// r16's BM=32 res_ln retile regressed (occupancy lever bidirectionally
// refuted); consolidating on the proven configuration.
// ---------------------------------------------------------------------------

#define S_LEN 8192
#define BATCH 4
#define DMODEL 256
#define NHEAD 8
#define WIN 64
#define NWIN 128
#define NLAYER 6
#define FFDIM 1024
#define MROWS (BATCH * S_LEN)

typedef float __attribute__((ext_vector_type(4))) f32x4;
typedef unsigned int __attribute__((ext_vector_type(2))) u32x2;
typedef unsigned short u16;
typedef unsigned short __attribute__((ext_vector_type(4))) u16x4;
typedef unsigned short __attribute__((ext_vector_type(8))) u16x8;

__device__ __forceinline__ u16 f2bf(float f) {
  unsigned u = __builtin_bit_cast(unsigned, f);
  u += 0x7fffu + ((u >> 16) & 1u);
  return (u16)(u >> 16);
}

__device__ __forceinline__ unsigned cvt_pk_bf16(float lo, float hi) {
  unsigned r;
  asm("v_cvt_pk_bf16_f32 %0, %1, %2" : "=v"(r) : "v"(lo), "v"(hi));
  return r;
}
__device__ __forceinline__ u32x2 pack_bf16x4(f32x4 v) {
  u32x2 o;
  o[0] = cvt_pk_bf16(v[0], v[1]);
  o[1] = cvt_pk_bf16(v[2], v[3]);
  return o;
}
__device__ __forceinline__ f32x4 unpack_bf16x4(u16x4 h) {
  f32x4 o;
  o[0] = __builtin_bit_cast(float, (unsigned)h[0] << 16);
  o[1] = __builtin_bit_cast(float, (unsigned)h[1] << 16);
  o[2] = __builtin_bit_cast(float, (unsigned)h[2] << 16);
  o[3] = __builtin_bit_cast(float, (unsigned)h[3] << 16);
  return o;
}

__device__ __forceinline__ float exp2_f(float x) {
  float r;
  asm("v_exp_f32 %0, %1" : "=v"(r) : "v"(x));
  return r;
}

// mfma16(d, P, Q): lane holds D[row = Q's l15-space][cols = P's l15-space
// at l4*4+j]  (validated rounds 3-16)
__device__ __forceinline__ void mfma16(f32x4& d, f32x4 a, f32x4 b) {
  asm volatile("v_mfma_f32_16x16x32_bf16 %0, %1, %2, %0"
               : "+v"(d) : "v"(a), "v"(b));
}
#define MFMA_FENCE() asm volatile("s_nop 7\n\ts_nop 7")

__device__ __forceinline__ void gload_lds16(const void* g, void* l) {
  __builtin_amdgcn_global_load_lds(
      (__attribute__((address_space(1))) void*)g,
      (__attribute__((address_space(3))) void*)l, 16, 0, 0);
}

__device__ __forceinline__ float gelu_f(float t) {
  float u = 0.7978845608028654f * (t + 0.044715f * t * t * t);
  float e = __expf(-2.0f * u);
  return t * __builtin_amdgcn_rcpf(1.0f + e);
}

// -------------------------------------------------- embed + LN1(layer 0) ---
__global__ __launch_bounds__(256) void embed_ln_kernel(
    const int* __restrict__ ids, const float* __restrict__ emb,
    const float* __restrict__ pos, const float* __restrict__ g,
    const float* __restrict__ b, u16* __restrict__ x, u16* __restrict__ xb) {
  int wid = threadIdx.x >> 6, lane = threadIdx.x & 63;
  int r = blockIdx.x * 4 + wid;
  int s = r & (S_LEN - 1);
  int id = ids[r];
  f32x4 e = *(const f32x4*)(emb + (size_t)id * DMODEL + lane * 4);
  f32x4 p = *(const f32x4*)(pos + (size_t)s * DMODEL + lane * 4);
  f32x4 v = e + p;
  *(u32x2*)(x + (size_t)r * DMODEL + lane * 4) = pack_bf16x4(v);
  float sm = v[0] + v[1] + v[2] + v[3];
  float q = v[0] * v[0] + v[1] * v[1] + v[2] * v[2] + v[3] * v[3];
  for (int off = 32; off; off >>= 1) {
    sm += __shfl_xor(sm, off, 64);
    q += __shfl_xor(q, off, 64);
  }
  float mean = sm * (1.0f / DMODEL);
  float var = q * (1.0f / DMODEL) - mean * mean;
  float rs = rsqrtf(var + 1e-5f);
  f32x4 gg = *(const f32x4*)(g + lane * 4);
  f32x4 bb = *(const f32x4*)(b + lane * 4);
  f32x4 o;
  for (int j = 0; j < 4; ++j) o[j] = (v[j] - mean) * rs * gg[j] + bb[j];
  *(u32x2*)(xb + (size_t)r * DMODEL + lane * 4) = pack_bf16x4(o);
}

// ----------------------------------------------------------------- zero ----
__global__ void zero_kernel(float* __restrict__ p, int n4) {
  int i = blockIdx.x * blockDim.x + threadIdx.x;
  int stride = gridDim.x * blockDim.x;
  f32x4 z = {0.f, 0.f, 0.f, 0.f};
  for (; i < n4; i += stride) ((f32x4*)p)[i] = z;
}

// ------------------------------ tiled weight transpose+cast (via LDS) ------
__global__ __launch_bounds__(256) void tcast_tile_kernel(
    const float* __restrict__ wq, const float* __restrict__ wk,
    const float* __restrict__ wv, const float* __restrict__ wo,
    const float* __restrict__ w1, const float* __restrict__ w2,
    u16* __restrict__ WqkvT, u16* __restrict__ WoT,
    u16* __restrict__ W1T, u16* __restrict__ W2T) {
  __shared__ u16 Ts[64 * 72];

  int tile = blockIdx.x;
  const float* srcBase;
  u16* dstBase;
  int K, N, rowOff, tileK, tileN;

  if (tile < 384) {
    int fam = tile / 96, local = tile % 96;
    int l = local >> 4, t = local & 15;
    K = 256;
    N = 256;
    tileK = t >> 2;
    tileN = t & 3;
    if (fam < 3) {
      const float* s = (fam == 0) ? wq : (fam == 1) ? wk : wv;
      srcBase = s + (size_t)l * 65536;
      dstBase = WqkvT + (size_t)l * 768 * 256;
      rowOff = fam * 256;
    } else {
      srcBase = wo + (size_t)l * 65536;
      dstBase = WoT + (size_t)l * 65536;
      rowOff = 0;
    }
  } else if (tile < 768) {
    int local = tile - 384;
    int l = local >> 6, t = local & 63;
    K = 256;
    N = 1024;
    tileK = t >> 4;
    tileN = t & 15;
    srcBase = w1 + (size_t)l * 262144;
    dstBase = W1T + (size_t)l * 262144;
    rowOff = 0;
  } else {
    int local = tile - 768;
    int l = local >> 6, t = local & 63;
    K = 1024;
    N = 256;
    tileK = t >> 2;
    tileN = t & 3;
    srcBase = w2 + (size_t)l * 262144;
    dstBase = W2T + (size_t)l * 262144;
    rowOff = 0;
  }

  int k0 = tileK * 64, n0 = tileN * 64;
  int tid = threadIdx.x;

#pragma unroll
  for (int p = 0; p < 4; ++p) {
    int ch = tid + p * 256;
    int r = ch >> 4, c4 = (ch & 15) * 4;
    f32x4 v = *(const f32x4*)(srcBase + (size_t)(k0 + r) * N + n0 + c4);
#pragma unroll
    for (int j = 0; j < 4; ++j) Ts[(c4 + j) * 72 + r] = f2bf(v[j]);
  }
  __syncthreads();

#pragma unroll
  for (int p = 0; p < 2; ++p) {
    int ch = tid + p * 256;
    int n = ch >> 3, kc = ch & 7;
    *(u16x8*)(dstBase + (size_t)(rowOff + n0 + n) * K + k0 + kc * 8) =
        *(const u16x8*)(Ts + n * 72 + kc * 8);
  }
}

// ------------------------------------------------------ plain GEMM (bf16) --
// 128x128 tile, 4 waves (2x2), BK=64, swizzled staged LDS.
template <bool GELU_ACT, bool HAS_BIAS, bool QKV>
__global__ __launch_bounds__(256) void gemm_bf16(
    const u16* __restrict__ A, const u16* __restrict__ Bt,
    u16* __restrict__ C, u16* __restrict__ Vt, const float* __restrict__ bias,
    int N, int K, int nx) {
  __shared__ u16 As[128 * 64];
  __shared__ u16 Bs[128 * 64];

  int nwg = gridDim.x;
  int bid = blockIdx.x;
  int w8 = (bid & 7) * (nwg >> 3) + (bid >> 3);
  int cx = w8 % nx, ry = w8 / nx;
  int bm = ry * 128, bn = cx * 128;

  int tid = threadIdx.x, lane = tid & 63, wid = tid >> 6;
  int l15 = lane & 15, l4 = lane >> 4;
  int wm = wid >> 1, wn = wid & 1;

  const u16* Ab = A + (size_t)bm * K;
  const u16* Bb = Bt + (size_t)bn * K;

  f32x4 acc[4][4] = {};

  for (int kt = 0; kt < K; kt += 64) {
#pragma unroll
    for (int i = 0; i < 4; ++i) {
      int s = tid + i * 256;
      int r = s >> 3, c = (s & 7) ^ (r & 7);
      gload_lds16(Ab + (size_t)r * K + kt + c * 8,
                  (char*)As + (wid * 64 + i * 256) * 16);
    }
#pragma unroll
    for (int i = 0; i < 4; ++i) {
      int s = tid + i * 256;
      int r = s >> 3, c = (s & 7) ^ (r & 7);
      gload_lds16(Bb + (size_t)r * K + kt + c * 8,
                  (char*)Bs + (wid * 64 + i * 256) * 16);
    }
    __syncthreads();
#pragma unroll
    for (int t = 0; t < 2; ++t) {
      f32x4 af[4], bf[4];
#pragma unroll
      for (int m = 0; m < 4; ++m) {
        int r = wm * 64 + m * 16 + l15;
        af[m] = ((const f32x4*)As)[r * 8 + ((t * 4 + l4) ^ (r & 7))];
      }
#pragma unroll
      for (int n = 0; n < 4; ++n) {
        int r = wn * 64 + n * 16 + l15;
        bf[n] = ((const f32x4*)Bs)[r * 8 + ((t * 4 + l4) ^ (r & 7))];
      }
#pragma unroll
      for (int m = 0; m < 4; ++m)
#pragma unroll
        for (int n = 0; n < 4; ++n) mfma16(acc[m][n], bf[n], af[m]);
    }
    __syncthreads();
  }
  MFMA_FENCE();

  int colB = bn + wn * 64;
  if (QKV && colB >= 512) {
#pragma unroll
    for (int m = 0; m < 4; ++m) {
      int row = bm + wm * 64 + m * 16 + l15;
      int bb = row >> 13, s = row & (S_LEN - 1);
#pragma unroll
      for (int n = 0; n < 4; ++n)
#pragma unroll
        for (int j = 0; j < 4; ++j) {
          int col = colB + n * 16 + l4 * 4 + j;
          Vt[((size_t)(bb * 256 + (col - 512))) * S_LEN + s] =
              f2bf(acc[m][n][j]);
        }
    }
    return;
  }
  f32x4 bv[4];
#pragma unroll
  for (int n = 0; n < 4; ++n)
    bv[n] = HAS_BIAS ? *(const f32x4*)(bias + colB + n * 16 + l4 * 4)
                     : (f32x4){0.f, 0.f, 0.f, 0.f};
#pragma unroll
  for (int m = 0; m < 4; ++m) {
    int row = bm + wm * 64 + m * 16 + l15;
#pragma unroll
    for (int n = 0; n < 4; ++n) {
      f32x4 v = acc[m][n] + bv[n];
      if (GELU_ACT) {
#pragma unroll
        for (int j = 0; j < 4; ++j) v[j] = gelu_f(v[j]);
      }
      *(u32x2*)(C + (size_t)row * N + colB + n * 16 + l4 * 4) = pack_bf16x4(v);
    }
  }
}

// ------------------------------------- GEMM + residual (+bias) + LN fused --
// BM=64, BN=256 (full row), 4 waves (col-split), BK=64. Grid 512.
template <bool DO_LN>
__global__ __launch_bounds__(256) void gemm_res_ln(
    const u16* __restrict__ A, const u16* __restrict__ Bt,
    u16* __restrict__ x, u16* __restrict__ xb,
    const float* __restrict__ bias, const float* __restrict__ g,
    const float* __restrict__ b, int K) {
  __shared__ u16 As[64 * 64];
  __shared__ u16 Bs[256 * 64];
  __shared__ float redS[64][4];
  __shared__ float redQ[64][4];

  int nwg = gridDim.x;  // 512
  int bid = blockIdx.x;
  int bm = ((bid & 7) * (nwg >> 3) + (bid >> 3)) * 64;

  int tid = threadIdx.x, lane = tid & 63, wid = tid >> 6;
  int l15 = lane & 15, l4 = lane >> 4;

  const u16* Ab = A + (size_t)bm * K;
  f32x4 acc[4][4] = {};

  for (int kt = 0; kt < K; kt += 64) {
#pragma unroll
    for (int i = 0; i < 2; ++i) {
      int s = tid + i * 256;
      int r = s >> 3, c = (s & 7) ^ (r & 7);
      gload_lds16(Ab + (size_t)r * K + kt + c * 8,
                  (char*)As + (wid * 64 + i * 256) * 16);
    }
#pragma unroll
    for (int i = 0; i < 8; ++i) {
      int s = tid + i * 256;
      int r = s >> 3, c = (s & 7) ^ (r & 7);
      gload_lds16(Bt + (size_t)r * K + kt + c * 8,
                  (char*)Bs + (wid * 64 + i * 256) * 16);
    }
    __syncthreads();
#pragma unroll
    for (int t = 0; t < 2; ++t) {
      f32x4 af[4], bf[4];
#pragma unroll
      for (int m = 0; m < 4; ++m) {
        int r = m * 16 + l15;
        af[m] = ((const f32x4*)As)[r * 8 + ((t * 4 + l4) ^ (r & 7))];
      }
#pragma unroll
      for (int n = 0; n < 4; ++n) {
        int r = wid * 64 + n * 16 + l15;
        bf[n] = ((const f32x4*)Bs)[r * 8 + ((t * 4 + l4) ^ (r & 7))];
      }
#pragma unroll
      for (int m = 0; m < 4; ++m)
#pragma unroll
        for (int n = 0; n < 4; ++n) mfma16(acc[m][n], bf[n], af[m]);
    }
    __syncthreads();
  }
  MFMA_FENCE();

  int colB = wid * 64;
  f32x4 bv[4];
#pragma unroll
  for (int n = 0; n < 4; ++n)
    bv[n] = bias ? *(const f32x4*)(bias + colB + n * 16 + l4 * 4)
                 : (f32x4){0.f, 0.f, 0.f, 0.f};

#pragma unroll
  for (int m = 0; m < 4; ++m) {
    int r = m * 16 + l15;
    size_t rowoff = (size_t)(bm + r) * DMODEL + colB;
    float s = 0.f, q = 0.f;
#pragma unroll
    for (int n = 0; n < 4; ++n) {
      f32x4 xv = unpack_bf16x4(*(const u16x4*)(x + rowoff + n * 16 + l4 * 4));
      f32x4 v = acc[m][n] + bv[n] + xv;
      acc[m][n] = v;
      s += v[0] + v[1] + v[2] + v[3];
      q += v[0] * v[0] + v[1] * v[1] + v[2] * v[2] + v[3] * v[3];
    }
    if (DO_LN) {
      s += __shfl_xor(s, 16, 64);
      s += __shfl_xor(s, 32, 64);
      q += __shfl_xor(q, 16, 64);
      q += __shfl_xor(q, 32, 64);
      if (l4 == 0) {
        redS[r][wid] = s;
        redQ[r][wid] = q;
      }
    }
  }
  if (DO_LN) __syncthreads();

  f32x4 gv[4], bbv[4];
  if (DO_LN) {
#pragma unroll
    for (int n = 0; n < 4; ++n) {
      gv[n] = *(const f32x4*)(g + colB + n * 16 + l4 * 4);
      bbv[n] = *(const f32x4*)(b + colB + n * 16 + l4 * 4);
    }
  }
#pragma unroll
  for (int m = 0; m < 4; ++m) {
    int r = m * 16 + l15;
    size_t rowoff = (size_t)(bm + r) * DMODEL + colB;
    float mean = 0.f, rs = 0.f;
    if (DO_LN) {
      f32x4 sv = *(const f32x4*)redS[r];
      f32x4 qv = *(const f32x4*)redQ[r];
      float ssum = sv[0] + sv[1] + sv[2] + sv[3];
      float qsum = qv[0] + qv[1] + qv[2] + qv[3];
      mean = ssum * (1.0f / DMODEL);
      float var = qsum * (1.0f / DMODEL) - mean * mean;
      rs = rsqrtf(var + 1e-5f);
    }
#pragma unroll
    for (int n = 0; n < 4; ++n) {
      f32x4 v = acc[m][n];
      *(u32x2*)(x + rowoff + n * 16 + l4 * 4) = pack_bf16x4(v);
      if (DO_LN) {
        f32x4 o;
#pragma unroll
        for (int j = 0; j < 4; ++j)
          o[j] = (v[j] - mean) * rs * gv[n][j] + bbv[n][j];
        *(u32x2*)(xb + rowoff + n * 16 + l4 * 4) = pack_bf16x4(o);
      }
    }
  }
}

// ------------------------------------------------------------ attention ----
__global__ __launch_bounds__(256, 4) void attn_kernel(
    const u16* __restrict__ qkv, const u16* __restrict__ vt,
    const int* __restrict__ amask, u16* __restrict__ ao) {
  int win = blockIdx.x, h = blockIdx.y, b = blockIdx.z;
  int tid = threadIdx.x, lane = tid & 63, wid = tid >> 6;
  int l15 = lane & 15, l4 = lane >> 4;

  __shared__ u16 KPs[192 * 64];  // Ks [96][64] / Ps [192][64]
  __shared__ u16 Vts[96 * 64];
  __shared__ float bias[192];

  int t0 = win * WIN - WIN;

  if (tid < 192) {
    int t = t0 + tid;
    bias[tid] =
        (t >= 0 && t < S_LEN && amask[b * S_LEN + t] != 0) ? 0.0f : -1e9f;
  }
#pragma unroll
  for (int it = 0; it < 3; ++it) {
    int c = it * 256 + tid;
    int k = c >> 2, j = c & 3;
    int t = t0 + k;
    t = t < 0 ? 0 : (t >= S_LEN ? S_LEN - 1 : t);
    f32x4 kd = *(const f32x4*)(qkv + (size_t)(b * S_LEN + t) * 768 + 256 +
                               h * 32 + j * 8);
    int row = k >> 1;
    int cc = (((k & 1) << 2) | j) ^ (row & 7);
    *(f32x4*)(KPs + row * 64 + cc * 8) = kd;
  }
#pragma unroll
  for (int it = 0; it < 3; ++it) {
    int c = it * 256 + tid;
    int d = c / 24, kc = c - d * 24;
    int ts = t0 + kc * 8;
    ts = ts < 0 ? 0 : (ts > S_LEN - 8 ? S_LEN - 8 : ts);
    f32x4 vd = *(const f32x4*)(vt + ((size_t)((b * 8 + h) * 32 + d)) * S_LEN + ts);
    int row = d * 3 + (kc >> 3);
    int cc = (kc & 7) ^ (row & 7);
    *(f32x4*)(Vts + row * 64 + cc * 8) = vd;
  }
  __syncthreads();

  int qrow = b * S_LEN + win * WIN + wid * 16 + l15;
  f32x4 aq = *(const f32x4*)(qkv + (size_t)qrow * 768 + h * 32 + l4 * 8);

  f32x4 sacc[12] = {};
  int krb = l15 >> 1;
  int kcc = (((l15 & 1) << 2) | l4) ^ (krb & 7);
#pragma unroll
  for (int f = 0; f < 12; ++f) {
    f32x4 bk = *(const f32x4*)(KPs + (f * 8 + krb) * 64 + kcc * 8);
    mfma16(sacc[f], bk, aq);
  }
  MFMA_FENCE();

  const float scale2 = 0.17677669529663687f * 1.4426950408889634f;
  float mrow = -1e30f;
#pragma unroll
  for (int f = 0; f < 12; ++f) {
    f32x4 bi = *(const f32x4*)&bias[f * 16 + l4 * 4];
#pragma unroll
    for (int j = 0; j < 4; ++j) {
      float sv = fmaf(sacc[f][j], scale2, bi[j]);
      sacc[f][j] = sv;
      mrow = fmaxf(mrow, sv);
    }
  }
  mrow = fmaxf(mrow, __shfl_xor(mrow, 16, 64));
  mrow = fmaxf(mrow, __shfl_xor(mrow, 32, 64));

  float ssum = 0.f;
#pragma unroll
  for (int f = 0; f < 12; ++f)
#pragma unroll
    for (int j = 0; j < 4; ++j) {
      float p = exp2_f(sacc[f][j] - mrow);
      sacc[f][j] = p;
      ssum += p;
    }
  ssum += __shfl_xor(ssum, 16, 64);
  ssum += __shfl_xor(ssum, 32, 64);

  __syncthreads();

  int q = wid * 16 + l15;
#pragma unroll
  for (int f = 0; f < 12; ++f) {
    u32x2 pk;
    pk[0] = cvt_pk_bf16(sacc[f][0], sacc[f][1]);
    pk[1] = cvt_pk_bf16(sacc[f][2], sacc[f][3]);
    int kc = f * 2 + (l4 >> 1);
    int row = q * 3 + (kc >> 3);
    int cc = (kc & 7) ^ (row & 7);
    *(u32x2*)(KPs + row * 64 + cc * 8 + (l4 & 1) * 4) = pk;
  }
  __syncthreads();

  f32x4 oacc[2] = {};
#pragma unroll
  for (int kk = 0; kk < 6; ++kk) {
    int kc = kk * 4 + l4;
    int rowp = q * 3 + (kc >> 3);
    int ccp = (kc & 7) ^ (rowp & 7);
    f32x4 ap = *(const f32x4*)(KPs + rowp * 64 + ccp * 8);
#pragma unroll
    for (int nf = 0; nf < 2; ++nf) {
      int d = nf * 16 + l15;
      int rowv = d * 3 + (kc >> 3);
      int ccv = (kc & 7) ^ (rowv & 7);
      f32x4 bvv = *(const f32x4*)(Vts + rowv * 64 + ccv * 8);
      mfma16(oacc[nf], bvv, ap);
    }
  }
  MFMA_FENCE();

  float invv = 1.0f / ssum;
  size_t obase = (size_t)qrow * 256 + h * 32;
#pragma unroll
  for (int nf = 0; nf < 2; ++nf) {
    f32x4 v = oacc[nf] * invv;
    *(u32x2*)(ao + obase + nf * 16 + l4 * 4) = pack_bf16x4(v);
  }
}

// ------------------------------------------------------------- scan --------
__global__ __launch_bounds__(256) void scan_kernel(const int* __restrict__ wsrt,
                                                   int* __restrict__ tgt) {
  __shared__ int part[256];
  int b = blockIdx.x, tid = threadIdx.x;
  const int* src = wsrt + b * S_LEN;
  int* dst = tgt + b * S_LEN;
  int base = tid * 32;
  int loc[32];
  int s = 0;
#pragma unroll
  for (int i = 0; i < 32; ++i) {
    loc[i] = src[base + i];
    s += loc[i];
  }
  part[tid] = s;
  __syncthreads();
  for (int off = 1; off < 256; off <<= 1) {
    int v = (tid >= off) ? part[tid - off] : 0;
    __syncthreads();
    part[tid] += v;
    __syncthreads();
  }
  int cum = part[tid] - s;
#pragma unroll
  for (int i = 0; i < 32; ++i) {
    cum += loc[i];
    dst[base + i] = (loc[i] > 0) ? (cum - 1) : -1;
  }
}

// ------------------------------------------------- final LN + gather -------
__global__ __launch_bounds__(64) void gather_ln_kernel(
    const u16* __restrict__ x, const int* __restrict__ tgt,
    const float* __restrict__ g, const float* __restrict__ b,
    float* __restrict__ out) {
  int r = blockIdx.x;
  int tg = tgt[r];
  if (tg < 0) return;
  int bIdx = r >> 13;
  int lane = threadIdx.x;
  f32x4 v = unpack_bf16x4(*(const u16x4*)(x + (size_t)r * DMODEL + lane * 4));
  float s = v[0] + v[1] + v[2] + v[3];
  float q = v[0] * v[0] + v[1] * v[1] + v[2] * v[2] + v[3] * v[3];
  for (int off = 32; off; off >>= 1) {
    s += __shfl_xor(s, off, 64);
    q += __shfl_xor(q, off, 64);
  }
  float mean = s * (1.0f / DMODEL);
  float var = q * (1.0f / DMODEL) - mean * mean;
  float rs = rsqrtf(var + 1e-5f);
  f32x4 gg = *(const f32x4*)(g + lane * 4);
  f32x4 bb = *(const f32x4*)(b + lane * 4);
  f32x4 o;
  for (int j = 0; j < 4; ++j) o[j] = (v[j] - mean) * rs * gg[j] + bb[j];
  *(f32x4*)(out + (size_t)(bIdx * S_LEN + tg) * DMODEL + lane * 4) = o;
}

// ---------------------------------------------------------------------------
extern "C" void kernel_launch(void* const* d_in, const int* in_sizes, int n_in,
                              void* d_out, int out_size, void* d_ws,
                              size_t ws_size, hipStream_t stream) {
  const int* ids = (const int*)d_in[0];
  const int* amask = (const int*)d_in[1];
  const int* wstart = (const int*)d_in[2];
  const float* emb = (const float*)d_in[3];
  const float* pos = (const float*)d_in[4];
  const float* ln1g = (const float*)d_in[5];
  const float* ln1b = (const float*)d_in[6];
  const float* wq = (const float*)d_in[7];
  const float* wk = (const float*)d_in[8];
  const float* wv = (const float*)d_in[9];
  const float* wo = (const float*)d_in[10];
  const float* ln2g = (const float*)d_in[11];
  const float* ln2b = (const float*)d_in[12];
  const float* w1 = (const float*)d_in[13];
  const float* b1 = (const float*)d_in[14];
  const float* w2 = (const float*)d_in[15];
  const float* b2 = (const float*)d_in[16];
  const float* lnfg = (const float*)d_in[17];
  const float* lnfb = (const float*)d_in[18];

  char* ws = (char*)d_ws;
  const size_t OFF_X = 0;              // bf16 [32768][256]
  const size_t OFF_XB = 33554432;      // bf16 [32768][256]
  const size_t OFF_AO = 50331648;      // bf16 [32768][256]
  const size_t OFF_BIG = 67108864;     // bf16 qkv [32768][768]
  const size_t OFF_VT = 117440512;     // bf16 [256][8192] V^T
  const size_t OFF_WQKVT = 134217728;  // bf16 [6][768][256]
  const size_t OFF_WOT = 136577024;    // bf16 [6][256][256]
  const size_t OFF_W1T = 137363456;    // bf16 [6][1024][256]
  const size_t OFF_W2T = 140509184;    // bf16 [6][256][1024]
  const size_t OFF_TGT = 143654912;    // int [32768]
  const size_t NEEDED = 143785984;
  if (ws_size < NEEDED) return;

  u16* x = (u16*)(ws + OFF_X);
  u16* xb = (u16*)(ws + OFF_XB);
  u16* ao = (u16*)(ws + OFF_AO);
  u16* big = (u16*)(ws + OFF_BIG);
  u16* vt = (u16*)(ws + OFF_VT);
  u16* WqkvT = (u16*)(ws + OFF_WQKVT);
  u16* WoT = (u16*)(ws + OFF_WOT);
  u16* W1T = (u16*)(ws + OFF_W1T);
  u16* W2T = (u16*)(ws + OFF_W2T);
  int* tgt = (int*)(ws + OFF_TGT);

  tcast_tile_kernel<<<1152, 256, 0, stream>>>(wq, wk, wv, wo, w1, w2,
                                              WqkvT, WoT, W1T, W2T);

  embed_ln_kernel<<<MROWS / 4, 256, 0, stream>>>(ids, emb, pos, ln1g, ln1b, x, xb);
  zero_kernel<<<2048, 256, 0, stream>>>((float*)d_out, out_size / 4);
  scan_kernel<<<BATCH, 256, 0, stream>>>(wstart, tgt);

  for (int l = 0; l < NLAYER; ++l) {
    gemm_bf16<false, false, true><<<1536, 256, 0, stream>>>(
        xb, WqkvT + (size_t)l * 768 * 256, big, vt, nullptr, 768, 256, 6);
    attn_kernel<<<dim3(NWIN, NHEAD, BATCH), 256, 0, stream>>>(big, vt, amask, ao);
    gemm_res_ln<true><<<MROWS / 64, 256, 0, stream>>>(
        ao, WoT + (size_t)l * 256 * 256, x, xb, nullptr,
        ln2g + l * DMODEL, ln2b + l * DMODEL, 256);
    gemm_bf16<true, true, false><<<2048, 256, 0, stream>>>(
        xb, W1T + (size_t)l * 1024 * 256, big, nullptr, b1 + l * FFDIM, 1024, 256, 8);
    if (l < NLAYER - 1) {
      gemm_res_ln<true><<<MROWS / 64, 256, 0, stream>>>(
          big, W2T + (size_t)l * 256 * 1024, x, xb, b2 + l * DMODEL,
          ln1g + (l + 1) * DMODEL, ln1b + (l + 1) * DMODEL, 1024);
    } else {
      gemm_res_ln<false><<<MROWS / 64, 256, 0, stream>>>(
          big, W2T + (size_t)l * 256 * 1024, x, nullptr, b2 + l * DMODEL,
          nullptr, nullptr, 1024);
    }
  }

  gather_ln_kernel<<<MROWS, 64, 0, stream>>>(x, tgt, lnfg, lnfb, (float*)d_out);
}